// Round 15
// baseline (280.130 us; speedup 1.0000x reference)
//
#include <hip/hip_runtime.h>
#include <hip/hip_bf16.h>
#include <hip/hip_fp16.h>
#include <math.h>

#define N_NODES 100000
#define N_EDGES 3200000
#define ET (N_EDGES + N_NODES)
#define F_IN 128
#define HID 32
#define NCLS 40
#define NEG 0.2f

// bucket sort geometry
#define NB 782
#define CHUNK 4096
#define NBLK 782
#define BCAP 5120
#define NB1 299                     // scan_a block count (2048 elems each)
// gemm: 64 rows/block, 2r x 4c per thread; x read direct from global
#define GROWS 64
#define GEMM_BLKS ((N_NODES + GROWS - 1) / GROWS)   // 1563

// one wave computes the 299-entry exclusive scan of bsums into bscan[]
// (replaces the k_scan_b launch; bsums is L2-resident, cost ~sub-us/block)
#define BSUM_SCAN(bscan, bsums)                                                   \
    if (t < 64) {                                                                 \
        int base5 = t * 5;                                                        \
        int bv0 = (base5     < NB1) ? bsums[base5]     : 0;                       \
        int bv1 = (base5 + 1 < NB1) ? bsums[base5 + 1] : 0;                       \
        int bv2 = (base5 + 2 < NB1) ? bsums[base5 + 2] : 0;                       \
        int bv3 = (base5 + 3 < NB1) ? bsums[base5 + 3] : 0;                       \
        int bv4 = (base5 + 4 < NB1) ? bsums[base5 + 4] : 0;                       \
        int bs = bv0 + bv1 + bv2 + bv3 + bv4;                                     \
        int brun = bs;                                                            \
        for (int boff = 1; boff < 64; boff <<= 1) {                               \
            int bx = __shfl_up(brun, boff);                                       \
            if (t >= boff) brun += bx;                                            \
        }                                                                         \
        brun -= bs;                                                               \
        if (base5     < NB1) { bscan[base5]     = brun; brun += bv0; }            \
        if (base5 + 1 < NB1) { bscan[base5 + 1] = brun; brun += bv1; }            \
        if (base5 + 2 < NB1) { bscan[base5 + 2] = brun; brun += bv2; }            \
        if (base5 + 3 < NB1) { bscan[base5 + 3] = brun; brun += bv3; }            \
        if (base5 + 4 < NB1) { bscan[base5 + 4] = brun; }                         \
    }

// ---------------- merged: bucket histogram || GEMM1 || prep ----------------
__global__ __launch_bounds__(256) void k_hist_gemm(
    const int* __restrict__ dst, int* __restrict__ Hm,
    const float* __restrict__ x, const float* __restrict__ W1,
    const float* __restrict__ a_s, const float* __restrict__ a_d,
    __half* __restrict__ h1h, float* __restrict__ s1, float* __restrict__ d1,
    const float* __restrict__ W2, const float* __restrict__ as2,
    const float* __restrict__ ad2, float* __restrict__ va_s, float* __restrict__ va_d) {
    __shared__ __align__(16) float Ws[F_IN * HID];     // 16KB union (hist needs 3.1KB)
    int t = threadIdx.x;
    if (blockIdx.x < NBLK) {
        // -------- histogram role (int4 loads) --------
        int* hist = (int*)Ws;
        int k = blockIdx.x;
        for (int i = t; i < NB; i += 256) hist[i] = 0;
        __syncthreads();
        int b4 = k * (CHUNK / 4);
#pragma unroll
        for (int j = 0; j < CHUNK / 4 / 256; j++) {       // 4 iters
            int i4 = b4 + j * 256 + t;
            if (i4 < N_EDGES / 4) {
                int4 d = ((const int4*)dst)[i4];
                atomicAdd(&hist[d.x >> 7], 1);
                atomicAdd(&hist[d.y >> 7], 1);
                atomicAdd(&hist[d.z >> 7], 1);
                atomicAdd(&hist[d.w >> 7], 1);
            }
        }
        __syncthreads();
        for (int i = t; i < NB; i += 256) Hm[i * NBLK + k] = hist[i];
    } else if (blockIdx.x < NBLK + GEMM_BLKS) {
        // -------- gemm role: 64 rows x 32 cols; thread = 2 rows x 4 cols --------
        int bb = blockIdx.x - NBLK;
        const float4* W4 = (const float4*)W1;
        float4* Ws4 = (float4*)Ws;
#pragma unroll
        for (int i = 0; i < F_IN * HID / 4 / 256; i++)    // 4
            Ws4[t + i * 256] = W4[t + i * 256];
        __syncthreads();
        int rp = t >> 3;                  // 0..31 (row pair)
        int cq = t & 7;                   // 0..7 (column quad)
        size_t v0 = (size_t)bb * GROWS + rp * 2;
        size_t v1 = v0 + 1;
        size_t r0c = (v0 < N_NODES) ? v0 : (size_t)(N_NODES - 1);
        size_t r1c = (v1 < N_NODES) ? v1 : (size_t)(N_NODES - 1);
        const float4* xa4 = (const float4*)(x + r0c * F_IN);
        const float4* xb4 = (const float4*)(x + r1c * F_IN);
        const float4* Wc4 = (const float4*)Ws;    // idx = k*8 + cq
        float a00 = 0.f, a01 = 0.f, a02 = 0.f, a03 = 0.f;
        float a10 = 0.f, a11 = 0.f, a12 = 0.f, a13 = 0.f;
#pragma unroll
        for (int k4 = 0; k4 < F_IN / 4; k4++) {
            float4 xa = xa4[k4];
            float4 xb = xb4[k4];
            int kb = k4 * 4;
            float4 w0 = Wc4[(kb + 0) * 8 + cq];
            float4 w1 = Wc4[(kb + 1) * 8 + cq];
            float4 w2 = Wc4[(kb + 2) * 8 + cq];
            float4 w3 = Wc4[(kb + 3) * 8 + cq];
            a00 = fmaf(xa.x, w0.x, a00); a01 = fmaf(xa.x, w0.y, a01);
            a02 = fmaf(xa.x, w0.z, a02); a03 = fmaf(xa.x, w0.w, a03);
            a00 = fmaf(xa.y, w1.x, a00); a01 = fmaf(xa.y, w1.y, a01);
            a02 = fmaf(xa.y, w1.z, a02); a03 = fmaf(xa.y, w1.w, a03);
            a00 = fmaf(xa.z, w2.x, a00); a01 = fmaf(xa.z, w2.y, a01);
            a02 = fmaf(xa.z, w2.z, a02); a03 = fmaf(xa.z, w2.w, a03);
            a00 = fmaf(xa.w, w3.x, a00); a01 = fmaf(xa.w, w3.y, a01);
            a02 = fmaf(xa.w, w3.z, a02); a03 = fmaf(xa.w, w3.w, a03);
            a10 = fmaf(xb.x, w0.x, a10); a11 = fmaf(xb.x, w0.y, a11);
            a12 = fmaf(xb.x, w0.z, a12); a13 = fmaf(xb.x, w0.w, a13);
            a10 = fmaf(xb.y, w1.x, a10); a11 = fmaf(xb.y, w1.y, a11);
            a12 = fmaf(xb.y, w1.z, a12); a13 = fmaf(xb.y, w1.w, a13);
            a10 = fmaf(xb.z, w2.x, a10); a11 = fmaf(xb.z, w2.y, a11);
            a12 = fmaf(xb.z, w2.z, a12); a13 = fmaf(xb.z, w2.w, a13);
            a10 = fmaf(xb.w, w3.x, a10); a11 = fmaf(xb.w, w3.y, a11);
            a12 = fmaf(xb.w, w3.z, a12); a13 = fmaf(xb.w, w3.w, a13);
        }
        if (v0 < N_NODES) {
            __half2 p0 = __floats2half2_rn(a00, a01);
            __half2 p1 = __floats2half2_rn(a02, a03);
            uint2 u;
            u.x = *(const unsigned int*)&p0;
            u.y = *(const unsigned int*)&p1;
            *((uint2*)(h1h + v0 * HID + cq * 4)) = u;
        }
        if (v1 < N_NODES) {
            __half2 p0 = __floats2half2_rn(a10, a11);
            __half2 p1 = __floats2half2_rn(a12, a13);
            uint2 u;
            u.x = *(const unsigned int*)&p0;
            u.y = *(const unsigned int*)&p1;
            *((uint2*)(h1h + v1 * HID + cq * 4)) = u;
        }
        float4 asv = *(const float4*)(a_s + cq * 4);
        float4 adv = *(const float4*)(a_d + cq * 4);
        float p0s = a00 * asv.x + a01 * asv.y + a02 * asv.z + a03 * asv.w;
        float p0d = a00 * adv.x + a01 * adv.y + a02 * adv.z + a03 * adv.w;
        float p1s = a10 * asv.x + a11 * asv.y + a12 * asv.z + a13 * asv.w;
        float p1d = a10 * adv.x + a11 * adv.y + a12 * adv.z + a13 * adv.w;
#pragma unroll
        for (int off = 1; off <= 4; off <<= 1) {
            p0s += __shfl_xor(p0s, off); p0d += __shfl_xor(p0d, off);
            p1s += __shfl_xor(p1s, off); p1d += __shfl_xor(p1d, off);
        }
        if (cq == 0) {
            if (v0 < N_NODES) { s1[v0] = p0s; d1[v0] = p0d; }
            if (v1 < N_NODES) { s1[v1] = p1s; d1[v1] = p1d; }
        }
    } else {
        // -------- prep role --------
        if (t < HID) {
            float ps = 0.f, pd = 0.f;
            for (int c = 0; c < NCLS; c++) {
                float w = W2[t * NCLS + c];
                ps = fmaf(w, as2[c], ps);
                pd = fmaf(w, ad2[c], pd);
            }
            va_s[t] = ps;
            va_d[t] = pd;
        }
    }
}

// ---------------- exclusive scan, 2048 elems/block ----------
__global__ void k_scan_a(const int* __restrict__ in, int* __restrict__ out,
                         int* __restrict__ bsums, int L) {
    __shared__ int sd[256];
    int t = threadIdx.x, b = blockIdx.x;
    int base = b * 2048 + t * 8;
    int v[8];
    int ts = 0;
#pragma unroll
    for (int u = 0; u < 8; u++) {
        v[u] = (base + u < L) ? in[base + u] : 0;
        ts += v[u];
    }
    sd[t] = ts;
    __syncthreads();
    for (int off = 1; off < 256; off <<= 1) {
        int xx = (t >= off) ? sd[t - off] : 0;
        __syncthreads();
        sd[t] += xx;
        __syncthreads();
    }
    int run = sd[t] - ts;
    if (t == 255) bsums[b] = sd[255];
#pragma unroll
    for (int u = 0; u < 8; u++) {
        if (base + u < L) out[base + u] = run;
        run += v[u];
    }
}

// ---------------- Pass A: scatter into buckets (bsums scan inlined) ----------
__global__ __launch_bounds__(256) void kA_scatter(
    const int* __restrict__ src, const int* __restrict__ dst,
    const int* __restrict__ Sx, const int* __restrict__ bsums,
    unsigned int* __restrict__ tmp) {
    __shared__ int hist[NB];                 // cur during slotting, gbase after
    __shared__ int lofs[NB];
    __shared__ int tsum[256];
    __shared__ int bscan[NB1 + 1];
    __shared__ unsigned int stage[CHUNK];
    __shared__ unsigned short bkt16[CHUNK];
    int t = threadIdx.x, k = blockIdx.x;
    for (int i = t; i < NB; i += 256) hist[i] = 0;
    BSUM_SCAN(bscan, bsums)
    __syncthreads();
    int myd[16], mys[16];
    int b4 = k * (CHUNK / 4);
#pragma unroll
    for (int j = 0; j < CHUNK / 4 / 256; j++) {           // 4 iters
        int i4 = b4 + j * 256 + t;
        if (i4 < N_EDGES / 4) {
            int4 d = ((const int4*)dst)[i4];
            int4 s = ((const int4*)src)[i4];
            myd[j * 4 + 0] = d.x; mys[j * 4 + 0] = s.x;
            myd[j * 4 + 1] = d.y; mys[j * 4 + 1] = s.y;
            myd[j * 4 + 2] = d.z; mys[j * 4 + 2] = s.z;
            myd[j * 4 + 3] = d.w; mys[j * 4 + 3] = s.w;
            atomicAdd(&hist[d.x >> 7], 1);
            atomicAdd(&hist[d.y >> 7], 1);
            atomicAdd(&hist[d.z >> 7], 1);
            atomicAdd(&hist[d.w >> 7], 1);
        } else {
#pragma unroll
            for (int u = 0; u < 4; u++) { myd[j * 4 + u] = -1; mys[j * 4 + u] = 0; }
        }
    }
    __syncthreads();
    int i0 = 4 * t;
    int h0 = (i0     < NB) ? hist[i0]     : 0;
    int h1 = (i0 + 1 < NB) ? hist[i0 + 1] : 0;
    int h2 = (i0 + 2 < NB) ? hist[i0 + 2] : 0;
    int h3 = (i0 + 3 < NB) ? hist[i0 + 3] : 0;
    int ts = h0 + h1 + h2 + h3;
    tsum[t] = ts;
    __syncthreads();
    for (int off = 1; off < 256; off <<= 1) {
        int xx = (t >= off) ? tsum[t - off] : 0;
        __syncthreads();
        tsum[t] += xx;
        __syncthreads();
    }
    int ex = tsum[t] - ts;
    if (i0     < NB) { lofs[i0]     = ex;                hist[i0]     = 0; }
    if (i0 + 1 < NB) { lofs[i0 + 1] = ex + h0;           hist[i0 + 1] = 0; }
    if (i0 + 2 < NB) { lofs[i0 + 2] = ex + h0 + h1;      hist[i0 + 2] = 0; }
    if (i0 + 3 < NB) { lofs[i0 + 3] = ex + h0 + h1 + h2; hist[i0 + 3] = 0; }
    __syncthreads();
#pragma unroll
    for (int j = 0; j < 16; j++) {
        if (myd[j] >= 0) {
            int bkt = myd[j] >> 7;
            int slot = lofs[bkt] + atomicAdd(&hist[bkt], 1);
            stage[slot] = ((unsigned int)(myd[j] & 127) << 17) | (unsigned int)mys[j];
            bkt16[slot] = (unsigned short)bkt;
        }
    }
    __syncthreads();
    // hist (dead as cur) <- per-bucket global write base minus lofs
    for (int b = t; b < NB; b += 256) {
        int idx = b * NBLK + k;
        hist[b] = Sx[idx] + bscan[idx >> 11] - lofs[b];
    }
    __syncthreads();
    int nvalid = min(CHUNK, N_EDGES - k * CHUNK);
    for (int i = t; i < nvalid; i += 256)
        tmp[hist[bkt16[i]] + i] = stage[i];
}

// ---------------- Pass B: per-bucket counting sort (bsums scan inlined) ----
__global__ __launch_bounds__(256) void kB_sort(
    const unsigned int* __restrict__ tmp, const int* __restrict__ Sx,
    const int* __restrict__ bsums,
    int* __restrict__ esrc, int* __restrict__ rs, int* __restrict__ deg) {
    __shared__ int ordered[BCAP + 128];
    __shared__ int cnt[128], lofs[128], cur[128], sc[128];
    __shared__ int bscan[NB1 + 1];
    int t = threadIdx.x, b = blockIdx.x;
    if (t < 128) { cnt[t] = 0; cur[t] = 0; }
    BSUM_SCAN(bscan, bsums)
    __syncthreads();
    int idx0 = b * NBLK;
    int myBase = Sx[idx0] + bscan[idx0 >> 11];
    int nextBase;
    if (b == NB - 1) nextBase = N_EDGES;
    else {
        int idx1 = (b + 1) * NBLK;
        nextBase = Sx[idx1] + bscan[idx1 >> 11];
    }
    int cntE = nextBase - myBase;
    int nNodes = min(128, N_NODES - b * 128);
    for (int i = t; i < cntE; i += 256) {
        unsigned int p = tmp[myBase + i];        // warms L2 for the re-read below
        atomicAdd(&cnt[p >> 17], 1);
    }
    __syncthreads();
    int val = 0;
    if (t < 128) { val = (t < nNodes) ? cnt[t] + 1 : 0; sc[t] = val; }
    __syncthreads();
    for (int off = 1; off < 128; off <<= 1) {
        int xx = 0;
        if (t < 128 && t >= off) xx = sc[t - off];
        __syncthreads();
        if (t < 128) sc[t] += xx;
        __syncthreads();
    }
    if (t < 128) lofs[t] = sc[t] - val;
    __syncthreads();
    if (t < nNodes) ordered[lofs[t]] = b * 128 + t;
    for (int i = t; i < cntE; i += 256) {
        unsigned int p = tmp[myBase + i];        // L2-hit re-read replaces LDS stage
        int n = p >> 17;
        int slot = lofs[n] + 1 + atomicAdd(&cur[n], 1);
        ordered[slot] = (int)(p & 0x1FFFF);
    }
    __syncthreads();
    int gb = myBase + b * 128;
    int totOut = cntE + nNodes;
    for (int i = t; i < totOut; i += 256) esrc[gb + i] = ordered[i];
    if (t < nNodes) {
        rs[b * 128 + t] = gb + lofs[t];
        deg[b * 128 + t] = cnt[t] + 1;
    }
}

// gather helper: 4-deep pipelined batch (round-0 proven form)
#define GATHER_BODY(SARR, TABLE)                                                  \
    float a0 = 0.f, a1 = 0.f, a2 = 0.f, a3 = 0.f,                                 \
          a4 = 0.f, a5 = 0.f, a6 = 0.f, a7 = 0.f;                                 \
    float den = 0.f;                                                              \
    int t = 0;                                                                    \
    for (; t + 16 <= cnt; t += 16) {                                              \
        int p0 = start + t + e;                                                   \
        int sa0 = esrc[p0];                                                       \
        int sa1 = esrc[p0 + 4];                                                   \
        int sa2 = esrc[p0 + 8];                                                   \
        int sa3 = esrc[p0 + 12];                                                  \
        float sv0 = SARR[sa0];                                                    \
        float sv1 = SARR[sa1];                                                    \
        float sv2 = SARR[sa2];                                                    \
        float sv3 = SARR[sa3];                                                    \
        uint4 hv0 = TABLE[(size_t)sa0 * 4 + q];                                   \
        uint4 hv1 = TABLE[(size_t)sa1 * 4 + q];                                   \
        uint4 hv2 = TABLE[(size_t)sa2 * 4 + q];                                   \
        uint4 hv3 = TABLE[(size_t)sa3 * 4 + q];                                   \
        float e0 = sv0 + dval; e0 = (e0 >= 0.f) ? e0 : NEG * e0;                  \
        float e1 = sv1 + dval; e1 = (e1 >= 0.f) ? e1 : NEG * e1;                  \
        float e2 = sv2 + dval; e2 = (e2 >= 0.f) ? e2 : NEG * e2;                  \
        float e3 = sv3 + dval; e3 = (e3 >= 0.f) ? e3 : NEG * e3;                  \
        float w0 = __expf(e0);                                                    \
        float w1 = __expf(e1);                                                    \
        float w2 = __expf(e2);                                                    \
        float w3 = __expf(e3);                                                    \
        den += (w0 + w1) + (w2 + w3);                                             \
        ACC8(w0, hv0); ACC8(w1, hv1); ACC8(w2, hv2); ACC8(w3, hv3);               \
    }                                                                             \
    for (; t < cnt; t += 4) {                                                     \
        int idx = t + e;                                                          \
        int sa = 0;                                                               \
        float w = 0.f;                                                            \
        if (idx < cnt) {                                                          \
            sa = esrc[start + idx];                                               \
            float ev = SARR[sa] + dval;                                           \
            ev = (ev >= 0.f) ? ev : NEG * ev;                                     \
            w = __expf(ev);                                                       \
        }                                                                         \
        uint4 hv = TABLE[(size_t)sa * 4 + q];                                     \
        ACC8(w, hv);                                                              \
        den += w;                                                                 \
    }

#define ACC8(W, HV)                                                               \
    {                                                                             \
        float2 f0 = __half22float2(*(const __half2*)&(HV).x);                     \
        float2 f1 = __half22float2(*(const __half2*)&(HV).y);                     \
        float2 f2 = __half22float2(*(const __half2*)&(HV).z);                     \
        float2 f3 = __half22float2(*(const __half2*)&(HV).w);                     \
        a0 = fmaf((W), f0.x, a0); a1 = fmaf((W), f0.y, a1);                       \
        a2 = fmaf((W), f1.x, a2); a3 = fmaf((W), f1.y, a3);                       \
        a4 = fmaf((W), f2.x, a4); a5 = fmaf((W), f2.y, a5);                       \
        a6 = fmaf((W), f3.x, a6); a7 = fmaf((W), f3.y, a7);                       \
    }

// ---------------- fused layer-1 sweep: 4 nodes/wave ----------
__global__ __launch_bounds__(256) void k_fused1(
    const int* __restrict__ rs, const int* __restrict__ deg, const int* __restrict__ esrc,
    const uint4* __restrict__ h1r, const float* __restrict__ s1, const float* __restrict__ d1,
    const float* __restrict__ b1, const float* __restrict__ va_s, const float* __restrict__ va_d,
    uint4* __restrict__ hrr, float* __restrict__ s2, float* __restrict__ d2) {
    int tid = threadIdx.x;
    int sub = tid & 15;      // lane within quarter-wave
    int q = sub & 3;         // 16B chunk of the row
    int e = sub >> 2;        // edge slot 0..3
    int v = blockIdx.x * 16 + (tid >> 4);
    int start = rs[v];
    int cnt = deg[v];
    float dval = d1[v];
    GATHER_BODY(s1, h1r)
    // reduce across the 4 edge lanes (bits 2,3)
#pragma unroll
    for (int off = 4; off <= 8; off <<= 1) {
        a0 += __shfl_xor(a0, off); a1 += __shfl_xor(a1, off);
        a2 += __shfl_xor(a2, off); a3 += __shfl_xor(a3, off);
        a4 += __shfl_xor(a4, off); a5 += __shfl_xor(a5, off);
        a6 += __shfl_xor(a6, off); a7 += __shfl_xor(a7, off);
        den += __shfl_xor(den, off);
    }
    if (e == 0) {
        float iden = 1.f / den;
        const float4* b4 = (const float4*)(b1 + q * 8);
        float4 bA = b4[0], bB = b4[1];
        float o0 = fmaxf(a0 * iden + bA.x, 0.f);
        float o1 = fmaxf(a1 * iden + bA.y, 0.f);
        float o2 = fmaxf(a2 * iden + bA.z, 0.f);
        float o3 = fmaxf(a3 * iden + bA.w, 0.f);
        float o4 = fmaxf(a4 * iden + bB.x, 0.f);
        float o5 = fmaxf(a5 * iden + bB.y, 0.f);
        float o6 = fmaxf(a6 * iden + bB.z, 0.f);
        float o7 = fmaxf(a7 * iden + bB.w, 0.f);
        __half2 p0 = __floats2half2_rn(o0, o1);
        __half2 p1 = __floats2half2_rn(o2, o3);
        __half2 p2 = __floats2half2_rn(o4, o5);
        __half2 p3 = __floats2half2_rn(o6, o7);
        uint4 ov;
        ov.x = *(const unsigned int*)&p0;
        ov.y = *(const unsigned int*)&p1;
        ov.z = *(const unsigned int*)&p2;
        ov.w = *(const unsigned int*)&p3;
        hrr[(size_t)v * 4 + q] = ov;
        const float4* vs4 = (const float4*)(va_s + q * 8);
        const float4* vd4 = (const float4*)(va_d + q * 8);
        float4 sA = vs4[0], sB = vs4[1], dA = vd4[0], dB = vd4[1];
        float ps = o0 * sA.x + o1 * sA.y + o2 * sA.z + o3 * sA.w
                 + o4 * sB.x + o5 * sB.y + o6 * sB.z + o7 * sB.w;
        float pd = o0 * dA.x + o1 * dA.y + o2 * dA.z + o3 * dA.w
                 + o4 * dB.x + o5 * dB.y + o6 * dB.z + o7 * dB.w;
        ps += __shfl_xor(ps, 1); pd += __shfl_xor(pd, 1);
        ps += __shfl_xor(ps, 2); pd += __shfl_xor(pd, 2);
        if (q == 0) { s2[v] = ps; d2[v] = pd; }
    }
}

// ---------------- fused layer-2 sweep: + @W2 + log_softmax ----
__global__ __launch_bounds__(256) void k_fused2(
    const int* __restrict__ rs, const int* __restrict__ deg, const int* __restrict__ esrc,
    const uint4* __restrict__ hrr, const float* __restrict__ s2, const float* __restrict__ d2,
    const float* __restrict__ W2, const float* __restrict__ b2, float* __restrict__ out) {
    __shared__ float W2s[HID * NCLS];     // 5 KB
    __shared__ float hragg[16][HID];      // 2 KB
    __shared__ float zbuf[16][NCLS];      // 2.5 KB
    __shared__ float gm[16], gl[16];
    int tid = threadIdx.x;
    for (int i = tid; i < HID * NCLS; i += 256) W2s[i] = W2[i];
    int sub = tid & 15;
    int q = sub & 3;
    int e = sub >> 2;
    int node = tid >> 4;               // 0..15 within block
    int v = blockIdx.x * 16 + node;
    int start = rs[v];
    int cnt = deg[v];
    float dval = d2[v];
    GATHER_BODY(s2, hrr)
#pragma unroll
    for (int off = 4; off <= 8; off <<= 1) {
        a0 += __shfl_xor(a0, off); a1 += __shfl_xor(a1, off);
        a2 += __shfl_xor(a2, off); a3 += __shfl_xor(a3, off);
        a4 += __shfl_xor(a4, off); a5 += __shfl_xor(a5, off);
        a6 += __shfl_xor(a6, off); a7 += __shfl_xor(a7, off);
        den += __shfl_xor(den, off);
    }
    if (e == 0) {
        float iden = 1.f / den;
        int cb = q * 8;
        hragg[node][cb + 0] = a0 * iden;
        hragg[node][cb + 1] = a1 * iden;
        hragg[node][cb + 2] = a2 * iden;
        hragg[node][cb + 3] = a3 * iden;
        hragg[node][cb + 4] = a4 * iden;
        hragg[node][cb + 5] = a5 * iden;
        hragg[node][cb + 6] = a6 * iden;
        hragg[node][cb + 7] = a7 * iden;
    }
    __syncthreads();
    // z = hragg @ W2 + b2, relu — 640 outputs over 256 threads
    for (int oi = tid; oi < 16 * NCLS; oi += 256) {
        int n = oi / NCLS, c = oi % NCLS;
        float z = 0.f;
#pragma unroll
        for (int k = 0; k < HID; k++)
            z = fmaf(hragg[n][k], W2s[k * NCLS + c], z);
        zbuf[n][c] = fmaxf(z + b2[c], 0.f);
    }
    __syncthreads();
    if (tid < 16) {
        float mx = -INFINITY;
        for (int c = 0; c < NCLS; c++) mx = fmaxf(mx, zbuf[tid][c]);
        float se = 0.f;
        for (int c = 0; c < NCLS; c++) se += __expf(zbuf[tid][c] - mx);
        gm[tid] = mx;
        gl[tid] = logf(se);
    }
    __syncthreads();
    for (int oi = tid; oi < 16 * NCLS; oi += 256) {
        int n = oi / NCLS, c = oi % NCLS;
        out[(size_t)(blockIdx.x * 16 + n) * NCLS + c] = zbuf[n][c] - gm[n] - gl[n];
    }
}

// ---------------- launch ----------------

extern "C" void kernel_launch(void* const* d_in, const int* in_sizes, int n_in,
                              void* d_out, int out_size, void* d_ws, size_t ws_size,
                              hipStream_t stream) {
    (void)in_sizes; (void)n_in; (void)out_size; (void)ws_size;
    const float* x   = (const float*)d_in[0];
    const int*   ei  = (const int*)d_in[1];
    const float* W1  = (const float*)d_in[2];
    const float* as1 = (const float*)d_in[3];
    const float* ad1 = (const float*)d_in[4];
    const float* b1  = (const float*)d_in[5];
    const float* W2  = (const float*)d_in[6];
    const float* as2 = (const float*)d_in[7];
    const float* ad2 = (const float*)d_in[8];
    const float* b2  = (const float*)d_in[9];
    float* out = (float*)d_out;
    const int* srcA = ei;
    const int* dstA = ei + N_EDGES;

    char* w = (char*)d_ws;
    size_t off = 0;
    auto alloc = [&](size_t bytes) {
        char* p = w + off;
        off = (off + bytes + 255) & ~(size_t)255;
        return p;
    };
    int* esrc     = (int*)alloc((size_t)ET * 4);
    int* rs       = (int*)alloc((size_t)N_NODES * 4);
    int* deg      = (int*)alloc((size_t)N_NODES * 4);
    char* region1 = alloc((size_t)N_NODES * HID * 4);   // first 2.4MB: Sx; tail 6.4MB: h1h
    float* s1     = (float*)alloc((size_t)N_NODES * 4);
    float* d1     = (float*)alloc((size_t)N_NODES * 4);
    char* region2 = alloc((size_t)N_EDGES * 4 + 1024);  // Hm, then tmp, then hrt
    float* s2     = (float*)alloc((size_t)N_NODES * 4);
    float* d2     = (float*)alloc((size_t)N_NODES * 4);
    float* va_s   = (float*)alloc(HID * 4);
    float* va_d   = (float*)alloc(HID * 4);
    int* bsums    = (int*)alloc(1024 * 4);

    const int L = NB * NBLK;                     // 611,524 (2.45 MB)
    int* Hm = (int*)region2;
    int* Sx = (int*)region1;                     // 2.45 MB < 6.4 MB h1h offset
    __half* h1h = (__half*)(region1 + (size_t)N_NODES * HID * 2);
    unsigned int* tmp = (unsigned int*)region2;
    __half* hrt = (__half*)region2;              // hr fp16 rows after build

    int nb1 = (L + 2047) / 2048;                 // 299 == NB1
    hipLaunchKernelGGL(k_hist_gemm, dim3(NBLK + GEMM_BLKS + 1), dim3(256), 0, stream,
                       dstA, Hm, x, W1, as1, ad1, h1h, s1, d1,
                       W2, as2, ad2, va_s, va_d);
    hipLaunchKernelGGL(k_scan_a, dim3(nb1), dim3(256), 0, stream, Hm, Sx, bsums, L);
    hipLaunchKernelGGL(kA_scatter, dim3(NBLK), dim3(256), 0, stream, srcA, dstA, Sx, bsums, tmp);
    hipLaunchKernelGGL(kB_sort, dim3(NB), dim3(256), 0, stream, tmp, Sx, bsums, esrc, rs, deg);
    hipLaunchKernelGGL(k_fused1, dim3(N_NODES / 16), dim3(256), 0, stream, rs, deg, esrc,
                       (const uint4*)h1h, s1, d1, b1, va_s, va_d,
                       (uint4*)hrt, s2, d2);
    hipLaunchKernelGGL(k_fused2, dim3(N_NODES / 16), dim3(256), 0, stream, rs, deg, esrc,
                       (const uint4*)hrt, s2, d2, W2, b2, out);
}

// Round 16
// 277.577 us; speedup vs baseline: 1.0092x; 1.0092x over previous
//
#include <hip/hip_runtime.h>
#include <hip/hip_bf16.h>
#include <hip/hip_fp16.h>
#include <math.h>

#define N_NODES 100000
#define N_EDGES 3200000
#define ET (N_EDGES + N_NODES)
#define F_IN 128
#define HID 32
#define NCLS 40
#define NEG 0.2f

// bucket sort geometry
#define NB 782
#define CHUNK 4096
#define NBLK 782
#define BCAP 5120
#define NB1 299                     // scan_a block count (2048 elems each)
// gemm: 64 rows/block, 2r x 4c per thread; x read direct from global
#define GROWS 64
#define GEMM_BLKS ((N_NODES + GROWS - 1) / GROWS)   // 1563

// one wave computes the 299-entry exclusive scan of bsums into bscan[]
#define BSUM_SCAN(bscan, bsums)                                                   \
    if (t < 64) {                                                                 \
        int base5 = t * 5;                                                        \
        int bv0 = (base5     < NB1) ? bsums[base5]     : 0;                       \
        int bv1 = (base5 + 1 < NB1) ? bsums[base5 + 1] : 0;                       \
        int bv2 = (base5 + 2 < NB1) ? bsums[base5 + 2] : 0;                       \
        int bv3 = (base5 + 3 < NB1) ? bsums[base5 + 3] : 0;                       \
        int bv4 = (base5 + 4 < NB1) ? bsums[base5 + 4] : 0;                       \
        int bs = bv0 + bv1 + bv2 + bv3 + bv4;                                     \
        int brun = bs;                                                            \
        for (int boff = 1; boff < 64; boff <<= 1) {                               \
            int bx = __shfl_up(brun, boff);                                       \
            if (t >= boff) brun += bx;                                            \
        }                                                                         \
        brun -= bs;                                                               \
        if (base5     < NB1) { bscan[base5]     = brun; brun += bv0; }            \
        if (base5 + 1 < NB1) { bscan[base5 + 1] = brun; brun += bv1; }            \
        if (base5 + 2 < NB1) { bscan[base5 + 2] = brun; brun += bv2; }            \
        if (base5 + 3 < NB1) { bscan[base5 + 3] = brun; brun += bv3; }            \
        if (base5 + 4 < NB1) { bscan[base5 + 4] = brun; }                         \
    }

// ---------------- histogram (+ prep in last block) ----------------
// gemm moved OUT (now overlaps scatter); hist back to 3.1KB LDS.
__global__ __launch_bounds__(256) void k_hist_prep(
    const int* __restrict__ dst, int* __restrict__ Hm,
    const float* __restrict__ W2, const float* __restrict__ as2,
    const float* __restrict__ ad2, float* __restrict__ va_s, float* __restrict__ va_d) {
    __shared__ int hist[NB];
    int t = threadIdx.x;
    if (blockIdx.x == NBLK) {
        if (t < HID) {
            float ps = 0.f, pd = 0.f;
            for (int c = 0; c < NCLS; c++) {
                float w = W2[t * NCLS + c];
                ps = fmaf(w, as2[c], ps);
                pd = fmaf(w, ad2[c], pd);
            }
            va_s[t] = ps;
            va_d[t] = pd;
        }
        return;
    }
    int k = blockIdx.x;
    for (int i = t; i < NB; i += 256) hist[i] = 0;
    __syncthreads();
    int b4 = k * (CHUNK / 4);
#pragma unroll
    for (int j = 0; j < CHUNK / 4 / 256; j++) {       // 4 iters
        int i4 = b4 + j * 256 + t;
        if (i4 < N_EDGES / 4) {
            int4 d = ((const int4*)dst)[i4];
            atomicAdd(&hist[d.x >> 7], 1);
            atomicAdd(&hist[d.y >> 7], 1);
            atomicAdd(&hist[d.z >> 7], 1);
            atomicAdd(&hist[d.w >> 7], 1);
        }
    }
    __syncthreads();
    for (int i = t; i < NB; i += 256) Hm[i * NBLK + k] = hist[i];
}

// ---------------- exclusive scan, 2048 elems/block ----------
__global__ void k_scan_a(const int* __restrict__ in, int* __restrict__ out,
                         int* __restrict__ bsums, int L) {
    __shared__ int sd[256];
    int t = threadIdx.x, b = blockIdx.x;
    int base = b * 2048 + t * 8;
    int v[8];
    int ts = 0;
#pragma unroll
    for (int u = 0; u < 8; u++) {
        v[u] = (base + u < L) ? in[base + u] : 0;
        ts += v[u];
    }
    sd[t] = ts;
    __syncthreads();
    for (int off = 1; off < 256; off <<= 1) {
        int xx = (t >= off) ? sd[t - off] : 0;
        __syncthreads();
        sd[t] += xx;
        __syncthreads();
    }
    int run = sd[t] - ts;
    if (t == 255) bsums[b] = sd[255];
#pragma unroll
    for (int u = 0; u < 8; u++) {
        if (base + u < L) out[base + u] = run;
        run += v[u];
    }
}

// ---------------- merged: scatter || GEMM1 ----------------
// scatter needs 33.1KB LDS; gemm 16KB -> union 33.1KB == scatter's own
// footprint, so scatter occupancy unchanged and gemm backfills spare CU
// capacity during the longest build stage (the round-6 trick, repositioned).
#define SMEM_STAGE  0                           // uint  [4096]  16384B
#define SMEM_BKT16  16384                       // ushort[4096]   8192B
#define SMEM_HIST   (16384 + 8192)              // int   [782]    3128B
#define SMEM_LOFS   (SMEM_HIST + 3128)          // int   [782]    3128B
#define SMEM_TSUM   (SMEM_LOFS + 3128)          // int   [256]    1024B
#define SMEM_BSCAN  (SMEM_TSUM + 1024)          // int   [300]    1200B
#define SMEM_TOTAL  (SMEM_BSCAN + 1200)         // 33056B

__global__ __launch_bounds__(256) void k_scatter_gemm(
    const int* __restrict__ src, const int* __restrict__ dst,
    const int* __restrict__ Sx, const int* __restrict__ bsums,
    unsigned int* __restrict__ tmp,
    const float* __restrict__ x, const float* __restrict__ W1,
    const float* __restrict__ a_s, const float* __restrict__ a_d,
    __half* __restrict__ h1h, float* __restrict__ s1, float* __restrict__ d1) {
    __shared__ __align__(16) char smem[SMEM_TOTAL];
    int t = threadIdx.x;
    if (blockIdx.x < NBLK) {
        // -------- scatter role --------
        unsigned int* stage = (unsigned int*)(smem + SMEM_STAGE);
        unsigned short* bkt16 = (unsigned short*)(smem + SMEM_BKT16);
        int* hist = (int*)(smem + SMEM_HIST);    // cur during slotting, gbase after
        int* lofs = (int*)(smem + SMEM_LOFS);
        int* tsum = (int*)(smem + SMEM_TSUM);
        int* bscan = (int*)(smem + SMEM_BSCAN);
        int k = blockIdx.x;
        for (int i = t; i < NB; i += 256) hist[i] = 0;
        BSUM_SCAN(bscan, bsums)
        __syncthreads();
        int myd[16], mys[16];
        int b4 = k * (CHUNK / 4);
#pragma unroll
        for (int j = 0; j < CHUNK / 4 / 256; j++) {           // 4 iters
            int i4 = b4 + j * 256 + t;
            if (i4 < N_EDGES / 4) {
                int4 d = ((const int4*)dst)[i4];
                int4 s = ((const int4*)src)[i4];
                myd[j * 4 + 0] = d.x; mys[j * 4 + 0] = s.x;
                myd[j * 4 + 1] = d.y; mys[j * 4 + 1] = s.y;
                myd[j * 4 + 2] = d.z; mys[j * 4 + 2] = s.z;
                myd[j * 4 + 3] = d.w; mys[j * 4 + 3] = s.w;
                atomicAdd(&hist[d.x >> 7], 1);
                atomicAdd(&hist[d.y >> 7], 1);
                atomicAdd(&hist[d.z >> 7], 1);
                atomicAdd(&hist[d.w >> 7], 1);
            } else {
#pragma unroll
                for (int u = 0; u < 4; u++) { myd[j * 4 + u] = -1; mys[j * 4 + u] = 0; }
            }
        }
        __syncthreads();
        int i0 = 4 * t;
        int h0 = (i0     < NB) ? hist[i0]     : 0;
        int h1 = (i0 + 1 < NB) ? hist[i0 + 1] : 0;
        int h2 = (i0 + 2 < NB) ? hist[i0 + 2] : 0;
        int h3 = (i0 + 3 < NB) ? hist[i0 + 3] : 0;
        int ts = h0 + h1 + h2 + h3;
        tsum[t] = ts;
        __syncthreads();
        for (int off = 1; off < 256; off <<= 1) {
            int xx = (t >= off) ? tsum[t - off] : 0;
            __syncthreads();
            tsum[t] += xx;
            __syncthreads();
        }
        int ex = tsum[t] - ts;
        if (i0     < NB) { lofs[i0]     = ex;                hist[i0]     = 0; }
        if (i0 + 1 < NB) { lofs[i0 + 1] = ex + h0;           hist[i0 + 1] = 0; }
        if (i0 + 2 < NB) { lofs[i0 + 2] = ex + h0 + h1;      hist[i0 + 2] = 0; }
        if (i0 + 3 < NB) { lofs[i0 + 3] = ex + h0 + h1 + h2; hist[i0 + 3] = 0; }
        __syncthreads();
#pragma unroll
        for (int j = 0; j < 16; j++) {
            if (myd[j] >= 0) {
                int bkt = myd[j] >> 7;
                int slot = lofs[bkt] + atomicAdd(&hist[bkt], 1);
                stage[slot] = ((unsigned int)(myd[j] & 127) << 17) | (unsigned int)mys[j];
                bkt16[slot] = (unsigned short)bkt;
            }
        }
        __syncthreads();
        for (int b = t; b < NB; b += 256) {
            int idx = b * NBLK + k;
            hist[b] = Sx[idx] + bscan[idx >> 11] - lofs[b];
        }
        __syncthreads();
        int nvalid = min(CHUNK, N_EDGES - k * CHUNK);
        for (int i = t; i < nvalid; i += 256)
            tmp[hist[bkt16[i]] + i] = stage[i];
    } else {
        // -------- gemm role: 64 rows x 32 cols; thread = 2 rows x 4 cols --------
        float* Ws = (float*)smem;
        int bb = blockIdx.x - NBLK;
        const float4* W4 = (const float4*)W1;
        float4* Ws4 = (float4*)Ws;
#pragma unroll
        for (int i = 0; i < F_IN * HID / 4 / 256; i++)    // 4
            Ws4[t + i * 256] = W4[t + i * 256];
        __syncthreads();
        int rp = t >> 3;                  // 0..31 (row pair)
        int cq = t & 7;                   // 0..7 (column quad)
        size_t v0 = (size_t)bb * GROWS + rp * 2;
        size_t v1 = v0 + 1;
        size_t r0c = (v0 < N_NODES) ? v0 : (size_t)(N_NODES - 1);
        size_t r1c = (v1 < N_NODES) ? v1 : (size_t)(N_NODES - 1);
        const float4* xa4 = (const float4*)(x + r0c * F_IN);
        const float4* xb4 = (const float4*)(x + r1c * F_IN);
        const float4* Wc4 = (const float4*)Ws;    // idx = k*8 + cq
        float a00 = 0.f, a01 = 0.f, a02 = 0.f, a03 = 0.f;
        float a10 = 0.f, a11 = 0.f, a12 = 0.f, a13 = 0.f;
#pragma unroll
        for (int k4 = 0; k4 < F_IN / 4; k4++) {
            float4 xa = xa4[k4];
            float4 xb = xb4[k4];
            int kb = k4 * 4;
            float4 w0 = Wc4[(kb + 0) * 8 + cq];
            float4 w1 = Wc4[(kb + 1) * 8 + cq];
            float4 w2 = Wc4[(kb + 2) * 8 + cq];
            float4 w3 = Wc4[(kb + 3) * 8 + cq];
            a00 = fmaf(xa.x, w0.x, a00); a01 = fmaf(xa.x, w0.y, a01);
            a02 = fmaf(xa.x, w0.z, a02); a03 = fmaf(xa.x, w0.w, a03);
            a00 = fmaf(xa.y, w1.x, a00); a01 = fmaf(xa.y, w1.y, a01);
            a02 = fmaf(xa.y, w1.z, a02); a03 = fmaf(xa.y, w1.w, a03);
            a00 = fmaf(xa.z, w2.x, a00); a01 = fmaf(xa.z, w2.y, a01);
            a02 = fmaf(xa.z, w2.z, a02); a03 = fmaf(xa.z, w2.w, a03);
            a00 = fmaf(xa.w, w3.x, a00); a01 = fmaf(xa.w, w3.y, a01);
            a02 = fmaf(xa.w, w3.z, a02); a03 = fmaf(xa.w, w3.w, a03);
            a10 = fmaf(xb.x, w0.x, a10); a11 = fmaf(xb.x, w0.y, a11);
            a12 = fmaf(xb.x, w0.z, a12); a13 = fmaf(xb.x, w0.w, a13);
            a10 = fmaf(xb.y, w1.x, a10); a11 = fmaf(xb.y, w1.y, a11);
            a12 = fmaf(xb.y, w1.z, a12); a13 = fmaf(xb.y, w1.w, a13);
            a10 = fmaf(xb.z, w2.x, a10); a11 = fmaf(xb.z, w2.y, a11);
            a12 = fmaf(xb.z, w2.z, a12); a13 = fmaf(xb.z, w2.w, a13);
            a10 = fmaf(xb.w, w3.x, a10); a11 = fmaf(xb.w, w3.y, a11);
            a12 = fmaf(xb.w, w3.z, a12); a13 = fmaf(xb.w, w3.w, a13);
        }
        if (v0 < N_NODES) {
            __half2 p0 = __floats2half2_rn(a00, a01);
            __half2 p1 = __floats2half2_rn(a02, a03);
            uint2 u;
            u.x = *(const unsigned int*)&p0;
            u.y = *(const unsigned int*)&p1;
            *((uint2*)(h1h + v0 * HID + cq * 4)) = u;
        }
        if (v1 < N_NODES) {
            __half2 p0 = __floats2half2_rn(a10, a11);
            __half2 p1 = __floats2half2_rn(a12, a13);
            uint2 u;
            u.x = *(const unsigned int*)&p0;
            u.y = *(const unsigned int*)&p1;
            *((uint2*)(h1h + v1 * HID + cq * 4)) = u;
        }
        float4 asv = *(const float4*)(a_s + cq * 4);
        float4 adv = *(const float4*)(a_d + cq * 4);
        float p0s = a00 * asv.x + a01 * asv.y + a02 * asv.z + a03 * asv.w;
        float p0d = a00 * adv.x + a01 * adv.y + a02 * adv.z + a03 * adv.w;
        float p1s = a10 * asv.x + a11 * asv.y + a12 * asv.z + a13 * asv.w;
        float p1d = a10 * adv.x + a11 * adv.y + a12 * adv.z + a13 * adv.w;
#pragma unroll
        for (int off = 1; off <= 4; off <<= 1) {
            p0s += __shfl_xor(p0s, off); p0d += __shfl_xor(p0d, off);
            p1s += __shfl_xor(p1s, off); p1d += __shfl_xor(p1d, off);
        }
        if (cq == 0) {
            if (v0 < N_NODES) { s1[v0] = p0s; d1[v0] = p0d; }
            if (v1 < N_NODES) { s1[v1] = p1s; d1[v1] = p1d; }
        }
    }
}

// ---------------- Pass B: per-bucket counting sort (bsums scan inlined) ----
__global__ __launch_bounds__(256) void kB_sort(
    const unsigned int* __restrict__ tmp, const int* __restrict__ Sx,
    const int* __restrict__ bsums,
    int* __restrict__ esrc, int* __restrict__ rs, int* __restrict__ deg) {
    __shared__ int ordered[BCAP + 128];
    __shared__ int cnt[128], lofs[128], cur[128], sc[128];
    __shared__ int bscan[NB1 + 1];
    int t = threadIdx.x, b = blockIdx.x;
    if (t < 128) { cnt[t] = 0; cur[t] = 0; }
    BSUM_SCAN(bscan, bsums)
    __syncthreads();
    int idx0 = b * NBLK;
    int myBase = Sx[idx0] + bscan[idx0 >> 11];
    int nextBase;
    if (b == NB - 1) nextBase = N_EDGES;
    else {
        int idx1 = (b + 1) * NBLK;
        nextBase = Sx[idx1] + bscan[idx1 >> 11];
    }
    int cntE = nextBase - myBase;
    int nNodes = min(128, N_NODES - b * 128);
    for (int i = t; i < cntE; i += 256) {
        unsigned int p = tmp[myBase + i];        // warms L2 for the re-read below
        atomicAdd(&cnt[p >> 17], 1);
    }
    __syncthreads();
    int val = 0;
    if (t < 128) { val = (t < nNodes) ? cnt[t] + 1 : 0; sc[t] = val; }
    __syncthreads();
    for (int off = 1; off < 128; off <<= 1) {
        int xx = 0;
        if (t < 128 && t >= off) xx = sc[t - off];
        __syncthreads();
        if (t < 128) sc[t] += xx;
        __syncthreads();
    }
    if (t < 128) lofs[t] = sc[t] - val;
    __syncthreads();
    if (t < nNodes) ordered[lofs[t]] = b * 128 + t;
    for (int i = t; i < cntE; i += 256) {
        unsigned int p = tmp[myBase + i];        // L2-hit re-read replaces LDS stage
        int n = p >> 17;
        int slot = lofs[n] + 1 + atomicAdd(&cur[n], 1);
        ordered[slot] = (int)(p & 0x1FFFF);
    }
    __syncthreads();
    int gb = myBase + b * 128;
    int totOut = cntE + nNodes;
    for (int i = t; i < totOut; i += 256) esrc[gb + i] = ordered[i];
    if (t < nNodes) {
        rs[b * 128 + t] = gb + lofs[t];
        deg[b * 128 + t] = cnt[t] + 1;
    }
}

// gather helper: 4-deep pipelined batch (round-0 proven form)
#define GATHER_BODY(SARR, TABLE)                                                  \
    float a0 = 0.f, a1 = 0.f, a2 = 0.f, a3 = 0.f,                                 \
          a4 = 0.f, a5 = 0.f, a6 = 0.f, a7 = 0.f;                                 \
    float den = 0.f;                                                              \
    int t = 0;                                                                    \
    for (; t + 16 <= cnt; t += 16) {                                              \
        int p0 = start + t + e;                                                   \
        int sa0 = esrc[p0];                                                       \
        int sa1 = esrc[p0 + 4];                                                   \
        int sa2 = esrc[p0 + 8];                                                   \
        int sa3 = esrc[p0 + 12];                                                  \
        float sv0 = SARR[sa0];                                                    \
        float sv1 = SARR[sa1];                                                    \
        float sv2 = SARR[sa2];                                                    \
        float sv3 = SARR[sa3];                                                    \
        uint4 hv0 = TABLE[(size_t)sa0 * 4 + q];                                   \
        uint4 hv1 = TABLE[(size_t)sa1 * 4 + q];                                   \
        uint4 hv2 = TABLE[(size_t)sa2 * 4 + q];                                   \
        uint4 hv3 = TABLE[(size_t)sa3 * 4 + q];                                   \
        float e0 = sv0 + dval; e0 = (e0 >= 0.f) ? e0 : NEG * e0;                  \
        float e1 = sv1 + dval; e1 = (e1 >= 0.f) ? e1 : NEG * e1;                  \
        float e2 = sv2 + dval; e2 = (e2 >= 0.f) ? e2 : NEG * e2;                  \
        float e3 = sv3 + dval; e3 = (e3 >= 0.f) ? e3 : NEG * e3;                  \
        float w0 = __expf(e0);                                                    \
        float w1 = __expf(e1);                                                    \
        float w2 = __expf(e2);                                                    \
        float w3 = __expf(e3);                                                    \
        den += (w0 + w1) + (w2 + w3);                                             \
        ACC8(w0, hv0); ACC8(w1, hv1); ACC8(w2, hv2); ACC8(w3, hv3);               \
    }                                                                             \
    for (; t < cnt; t += 4) {                                                     \
        int idx = t + e;                                                          \
        int sa = 0;                                                               \
        float w = 0.f;                                                            \
        if (idx < cnt) {                                                          \
            sa = esrc[start + idx];                                               \
            float ev = SARR[sa] + dval;                                           \
            ev = (ev >= 0.f) ? ev : NEG * ev;                                     \
            w = __expf(ev);                                                       \
        }                                                                         \
        uint4 hv = TABLE[(size_t)sa * 4 + q];                                     \
        ACC8(w, hv);                                                              \
        den += w;                                                                 \
    }

#define ACC8(W, HV)                                                               \
    {                                                                             \
        float2 f0 = __half22float2(*(const __half2*)&(HV).x);                     \
        float2 f1 = __half22float2(*(const __half2*)&(HV).y);                     \
        float2 f2 = __half22float2(*(const __half2*)&(HV).z);                     \
        float2 f3 = __half22float2(*(const __half2*)&(HV).w);                     \
        a0 = fmaf((W), f0.x, a0); a1 = fmaf((W), f0.y, a1);                       \
        a2 = fmaf((W), f1.x, a2); a3 = fmaf((W), f1.y, a3);                       \
        a4 = fmaf((W), f2.x, a4); a5 = fmaf((W), f2.y, a5);                       \
        a6 = fmaf((W), f3.x, a6); a7 = fmaf((W), f3.y, a7);                       \
    }

// ---------------- fused layer-1 sweep: 4 nodes/wave ----------
__global__ __launch_bounds__(256) void k_fused1(
    const int* __restrict__ rs, const int* __restrict__ deg, const int* __restrict__ esrc,
    const uint4* __restrict__ h1r, const float* __restrict__ s1, const float* __restrict__ d1,
    const float* __restrict__ b1, const float* __restrict__ va_s, const float* __restrict__ va_d,
    uint4* __restrict__ hrr, float* __restrict__ s2, float* __restrict__ d2) {
    int tid = threadIdx.x;
    int sub = tid & 15;      // lane within quarter-wave
    int q = sub & 3;         // 16B chunk of the row
    int e = sub >> 2;        // edge slot 0..3
    int v = blockIdx.x * 16 + (tid >> 4);
    int start = rs[v];
    int cnt = deg[v];
    float dval = d1[v];
    GATHER_BODY(s1, h1r)
    // reduce across the 4 edge lanes (bits 2,3)
#pragma unroll
    for (int off = 4; off <= 8; off <<= 1) {
        a0 += __shfl_xor(a0, off); a1 += __shfl_xor(a1, off);
        a2 += __shfl_xor(a2, off); a3 += __shfl_xor(a3, off);
        a4 += __shfl_xor(a4, off); a5 += __shfl_xor(a5, off);
        a6 += __shfl_xor(a6, off); a7 += __shfl_xor(a7, off);
        den += __shfl_xor(den, off);
    }
    if (e == 0) {
        float iden = 1.f / den;
        const float4* b4 = (const float4*)(b1 + q * 8);
        float4 bA = b4[0], bB = b4[1];
        float o0 = fmaxf(a0 * iden + bA.x, 0.f);
        float o1 = fmaxf(a1 * iden + bA.y, 0.f);
        float o2 = fmaxf(a2 * iden + bA.z, 0.f);
        float o3 = fmaxf(a3 * iden + bA.w, 0.f);
        float o4 = fmaxf(a4 * iden + bB.x, 0.f);
        float o5 = fmaxf(a5 * iden + bB.y, 0.f);
        float o6 = fmaxf(a6 * iden + bB.z, 0.f);
        float o7 = fmaxf(a7 * iden + bB.w, 0.f);
        __half2 p0 = __floats2half2_rn(o0, o1);
        __half2 p1 = __floats2half2_rn(o2, o3);
        __half2 p2 = __floats2half2_rn(o4, o5);
        __half2 p3 = __floats2half2_rn(o6, o7);
        uint4 ov;
        ov.x = *(const unsigned int*)&p0;
        ov.y = *(const unsigned int*)&p1;
        ov.z = *(const unsigned int*)&p2;
        ov.w = *(const unsigned int*)&p3;
        hrr[(size_t)v * 4 + q] = ov;
        const float4* vs4 = (const float4*)(va_s + q * 8);
        const float4* vd4 = (const float4*)(va_d + q * 8);
        float4 sA = vs4[0], sB = vs4[1], dA = vd4[0], dB = vd4[1];
        float ps = o0 * sA.x + o1 * sA.y + o2 * sA.z + o3 * sA.w
                 + o4 * sB.x + o5 * sB.y + o6 * sB.z + o7 * sB.w;
        float pd = o0 * dA.x + o1 * dA.y + o2 * dA.z + o3 * dA.w
                 + o4 * dB.x + o5 * dB.y + o6 * dB.z + o7 * dB.w;
        ps += __shfl_xor(ps, 1); pd += __shfl_xor(pd, 1);
        ps += __shfl_xor(ps, 2); pd += __shfl_xor(pd, 2);
        if (q == 0) { s2[v] = ps; d2[v] = pd; }
    }
}

// ---------------- fused layer-2 sweep: + @W2 + log_softmax ----
__global__ __launch_bounds__(256) void k_fused2(
    const int* __restrict__ rs, const int* __restrict__ deg, const int* __restrict__ esrc,
    const uint4* __restrict__ hrr, const float* __restrict__ s2, const float* __restrict__ d2,
    const float* __restrict__ W2, const float* __restrict__ b2, float* __restrict__ out) {
    __shared__ float W2s[HID * NCLS];     // 5 KB
    __shared__ float hragg[16][HID];      // 2 KB
    __shared__ float zbuf[16][NCLS];      // 2.5 KB
    __shared__ float gm[16], gl[16];
    int tid = threadIdx.x;
    for (int i = tid; i < HID * NCLS; i += 256) W2s[i] = W2[i];
    int sub = tid & 15;
    int q = sub & 3;
    int e = sub >> 2;
    int node = tid >> 4;               // 0..15 within block
    int v = blockIdx.x * 16 + node;
    int start = rs[v];
    int cnt = deg[v];
    float dval = d2[v];
    GATHER_BODY(s2, hrr)
#pragma unroll
    for (int off = 4; off <= 8; off <<= 1) {
        a0 += __shfl_xor(a0, off); a1 += __shfl_xor(a1, off);
        a2 += __shfl_xor(a2, off); a3 += __shfl_xor(a3, off);
        a4 += __shfl_xor(a4, off); a5 += __shfl_xor(a5, off);
        a6 += __shfl_xor(a6, off); a7 += __shfl_xor(a7, off);
        den += __shfl_xor(den, off);
    }
    if (e == 0) {
        float iden = 1.f / den;
        int cb = q * 8;
        hragg[node][cb + 0] = a0 * iden;
        hragg[node][cb + 1] = a1 * iden;
        hragg[node][cb + 2] = a2 * iden;
        hragg[node][cb + 3] = a3 * iden;
        hragg[node][cb + 4] = a4 * iden;
        hragg[node][cb + 5] = a5 * iden;
        hragg[node][cb + 6] = a6 * iden;
        hragg[node][cb + 7] = a7 * iden;
    }
    __syncthreads();
    // z = hragg @ W2 + b2, relu — 640 outputs over 256 threads
    for (int oi = tid; oi < 16 * NCLS; oi += 256) {
        int n = oi / NCLS, c = oi % NCLS;
        float z = 0.f;
#pragma unroll
        for (int k = 0; k < HID; k++)
            z = fmaf(hragg[n][k], W2s[k * NCLS + c], z);
        zbuf[n][c] = fmaxf(z + b2[c], 0.f);
    }
    __syncthreads();
    if (tid < 16) {
        float mx = -INFINITY;
        for (int c = 0; c < NCLS; c++) mx = fmaxf(mx, zbuf[tid][c]);
        float se = 0.f;
        for (int c = 0; c < NCLS; c++) se += __expf(zbuf[tid][c] - mx);
        gm[tid] = mx;
        gl[tid] = logf(se);
    }
    __syncthreads();
    for (int oi = tid; oi < 16 * NCLS; oi += 256) {
        int n = oi / NCLS, c = oi % NCLS;
        out[(size_t)(blockIdx.x * 16 + n) * NCLS + c] = zbuf[n][c] - gm[n] - gl[n];
    }
}

// ---------------- launch ----------------

extern "C" void kernel_launch(void* const* d_in, const int* in_sizes, int n_in,
                              void* d_out, int out_size, void* d_ws, size_t ws_size,
                              hipStream_t stream) {
    (void)in_sizes; (void)n_in; (void)out_size; (void)ws_size;
    const float* x   = (const float*)d_in[0];
    const int*   ei  = (const int*)d_in[1];
    const float* W1  = (const float*)d_in[2];
    const float* as1 = (const float*)d_in[3];
    const float* ad1 = (const float*)d_in[4];
    const float* b1  = (const float*)d_in[5];
    const float* W2  = (const float*)d_in[6];
    const float* as2 = (const float*)d_in[7];
    const float* ad2 = (const float*)d_in[8];
    const float* b2  = (const float*)d_in[9];
    float* out = (float*)d_out;
    const int* srcA = ei;
    const int* dstA = ei + N_EDGES;

    char* w = (char*)d_ws;
    size_t off = 0;
    auto alloc = [&](size_t bytes) {
        char* p = w + off;
        off = (off + bytes + 255) & ~(size_t)255;
        return p;
    };
    int* esrc     = (int*)alloc((size_t)ET * 4);
    int* rs       = (int*)alloc((size_t)N_NODES * 4);
    int* deg      = (int*)alloc((size_t)N_NODES * 4);
    char* region1 = alloc((size_t)N_NODES * HID * 4);   // first 2.4MB: Sx; tail 6.4MB: h1h
    float* s1     = (float*)alloc((size_t)N_NODES * 4);
    float* d1     = (float*)alloc((size_t)N_NODES * 4);
    char* region2 = alloc((size_t)N_EDGES * 4 + 1024);  // Hm, then tmp, then hrt
    float* s2     = (float*)alloc((size_t)N_NODES * 4);
    float* d2     = (float*)alloc((size_t)N_NODES * 4);
    float* va_s   = (float*)alloc(HID * 4);
    float* va_d   = (float*)alloc(HID * 4);
    int* bsums    = (int*)alloc(1024 * 4);

    const int L = NB * NBLK;                     // 611,524 (2.45 MB)
    int* Hm = (int*)region2;
    int* Sx = (int*)region1;                     // 2.45 MB < 6.4 MB h1h offset
    __half* h1h = (__half*)(region1 + (size_t)N_NODES * HID * 2);
    unsigned int* tmp = (unsigned int*)region2;
    __half* hrt = (__half*)region2;              // hr fp16 rows after build

    int nb1 = (L + 2047) / 2048;                 // 299 == NB1
    hipLaunchKernelGGL(k_hist_prep, dim3(NBLK + 1), dim3(256), 0, stream,
                       dstA, Hm, W2, as2, ad2, va_s, va_d);
    hipLaunchKernelGGL(k_scan_a, dim3(nb1), dim3(256), 0, stream, Hm, Sx, bsums, L);
    hipLaunchKernelGGL(k_scatter_gemm, dim3(NBLK + GEMM_BLKS), dim3(256), 0, stream,
                       srcA, dstA, Sx, bsums, tmp,
                       x, W1, as1, ad1, h1h, s1, d1);
    hipLaunchKernelGGL(kB_sort, dim3(NB), dim3(256), 0, stream, tmp, Sx, bsums, esrc, rs, deg);
    hipLaunchKernelGGL(k_fused1, dim3(N_NODES / 16), dim3(256), 0, stream, rs, deg, esrc,
                       (const uint4*)h1h, s1, d1, b1, va_s, va_d,
                       (uint4*)hrt, s2, d2);
    hipLaunchKernelGGL(k_fused2, dim3(N_NODES / 16), dim3(256), 0, stream, rs, deg, esrc,
                       (const uint4*)hrt, s2, d2, W2, b2, out);
}